// Round 8
// baseline (167.559 us; speedup 1.0000x reference)
//
#include <hip/hip_runtime.h>
#include <math.h>

// ============================================================================
// ROUND-16: DIAGNOSTIC BUILD #2 — decompose the ~97-us fixed remainder.
// REP_S=8 on k_gl1 / k_gate1 / k_gate2 (idempotent recompute; barrier at rep
// start guards LDS WAR). k_gemm1 / k_conv2 stay REP=1 (current best form).
// total ?= 132 + 7*S, S = true small-kernel sum. REVERT REP_S TO 1 NEXT ROUND.
// ============================================================================

typedef __attribute__((ext_vector_type(8))) short short8x;   // 8 x bf16 = 4 VGPRs
typedef __attribute__((ext_vector_type(4))) float float4x;   // MFMA 16x16 C/D frag
typedef unsigned short u16;
typedef unsigned int u32;

#define REP_S 8   // small-kernel repeats (diagnostic)

// ---- global_load_lds 16B: direct HBM/L2 -> LDS DMA (no VGPR round-trip)
typedef const u32 __attribute__((address_space(1)))* gas_p;
typedef u32 __attribute__((address_space(3)))* las_p;
__device__ __forceinline__ void gl_lds16(const void* g, void* l) {
    __builtin_amdgcn_global_load_lds((gas_p)g, (las_p)l, 16, 0, 0);
}

__device__ __forceinline__ float bf2f(u16 u) {
    return __uint_as_float(((u32)u) << 16);
}
__device__ __forceinline__ u16 f2bf(float f) {
    u32 u = __float_as_uint(f);
    u32 r = (u + 0x7fffu + ((u >> 16) & 1u)) >> 16;   // round-to-nearest-even
    return (u16)r;
}
// monotone float<->u32 mapping (u-order == f-order), exact; for atomicMax on floats
__device__ __forceinline__ u32 fenc(float f) {
    u32 b = __float_as_uint(f);
    return b ^ (0x80000000u | (u32)((int)b >> 31));
}
__device__ __forceinline__ float fdec(u32 u) {
    u32 b = (u & 0x80000000u) ? (u ^ 0x80000000u) : ~u;
    return __uint_as_float(b);
}
// fast sigmoid (v_exp_f32 path); error ~2ulp, rounded to bf16 downstream anyway
__device__ __forceinline__ float fsig(float v) {
    return __builtin_amdgcn_rcpf(1.f + __expf(-v));
}
// fast exact-GELU: Abramowitz-Stegun 7.1.26 erf, max abs err 1.5e-7 (<< bf16 ulp).
__device__ __forceinline__ float fgelu(float v) {
    const float is2 = 0.70710678118654752f;
    float z = v * is2;
    float ax = fabsf(z);
    float t = __builtin_amdgcn_rcpf(1.f + 0.3275911f * ax);
    float p = ((((1.061405429f * t - 1.453152027f) * t) + 1.421413741f) * t - 0.284496736f) * t
              + 0.254829592f;
    float e = 1.f - p * t * __expf(-ax * ax);        // erf(|z|)
    float er = copysignf(e, z);
    return 0.5f * v * (1.f + er);
}

// ---------------------------------------------------------------- sizes
// B=4, H=W=96, C_in=64, C_hid=256, C_out=64, padded HP=98. c split: 8 groups x 32.
// 5-dispatch pipeline: gl1(+border+gl2init) -> gate1 -> gemm1 -> gate2 -> conv2.
// LEDGER (measured):
//   r14 REP=8 on gemm1+conv2: 7*(g1+c2)=241.7 -> g1+c2 ~= 34.5 us (warm, REP-build)
//   r12: one dispatch boundary <= 2 us (removing one: delta ~0)
//   r15: conv2 occupancy fix + gl_lds + swizzle -> delta ~0 total
//   poison fill: 256 MiB @ ~5.9 TB/s ~= 45 us, likely inside timed replay
//   => ~30-45 us of the 132 unattributed; gl1/gate1/gate2 never yet observed.
// NOTE (round-5): border-zero/gl2-init must precede gemm1 via dispatch boundary.
// NOTE (round-10 FAILED): conv2 g-split across waves regressed. (round-11 FAILED):
// never hand-roll cross-block sync (XCD L2 non-coherence). (round-12): folding
// gates is neutral.
// ws layout (bytes):
//   h2p   @ 4718592   : 4*8*98*98*32*2= 19,668,992 bf16 [b][g][98][98][32]
//   W1A   @ 24387584  : 4*256*64*2    = 131,072    bf16 [b][oc][c64]
//   W2A   @ 24518656  : 4*8*9*64*32*2 = 1,179,648  bf16 [b][g][k][oc][c32]
//   gl1   @ 25698304  : 4*64*4       = 1,024      fp32 per-(b,c) global max
//   gl2   @ 25796608  : 4*9*256*4    = 36,864     u32 fenc(max) [b][k=ki*3+kj][c]

// blocks 0..255: global max per (b,c); blocks 256..287: h2p border zero + gl2 init
// DIAGNOSTIC: body repeated REP_S times (idempotent).
__global__ __launch_bounds__(256) void k_gl1(const float* __restrict__ x, float* __restrict__ gl1,
                                             u32* __restrict__ h2p32, u32* __restrict__ gl2u) {
    if (blockIdx.x >= 256) {                        // border-zero duty (plane bi)
        int t = threadIdx.x;
        int plane_id = blockIdx.x - 256;
        u32* plane = h2p32 + plane_id * (98 * 98 * 16);
        #pragma unroll 1
        for (int rep = 0; rep < REP_S; rep++) {
            for (int i = t; i < 1568; i += 256) plane[i] = 0u;                  // row 0
            for (int i = t; i < 1568; i += 256) plane[97 * 98 * 16 + i] = 0u;   // row 97
            for (int i = t; i < 3072; i += 256) {                               // cols 0 & 97
                int r = (i >> 5) + 1;
                int p = ((i >> 4) & 1) * 97;
                int w = i & 15;
                plane[(r * 98 + p) * 16 + w] = 0u;
            }
            // gl2 init to u32 0 (== most-negative in fenc order)
            for (int i = plane_id * 288 + t; i < (plane_id + 1) * 288; i += 256)
                gl2u[i] = 0u;
        }
        return;
    }
    int b = blockIdx.x >> 6, c = blockIdx.x & 63;
    const float4* p = (const float4*)(x + (b * 64 + c) * 9216);
    __shared__ float red[256];
    #pragma unroll 1
    for (int rep = 0; rep < REP_S; rep++) {
        __syncthreads();                            // prior rep's red reads done
        float m = -1e30f;
        #pragma unroll
        for (int i = 0; i < 9; i++) {
            float4 v = p[i * 256 + threadIdx.x];
            m = fmaxf(m, fmaxf(fmaxf(v.x, v.y), fmaxf(v.z, v.w)));
        }
        red[threadIdx.x] = m;
        __syncthreads();
        for (int s = 128; s > 0; s >>= 1) {
            if (threadIdx.x < s) red[threadIdx.x] = fmaxf(red[threadIdx.x], red[threadIdx.x + s]);
            __syncthreads();
        }
        if (threadIdx.x == 0) gl1[b * 64 + c] = red[0];
    }
}

// fc1 gating -> W1A[b][oc=256][c=64]; 64 blocks = (b, slice16)
// DIAGNOSTIC: body repeated REP_S times (idempotent).
__global__ __launch_bounds__(256) void k_gate1(const float* __restrict__ gl1,
                                               const float* __restrict__ ce, const float* __restrict__ gd,
                                               const float* __restrict__ gd2, const float* __restrict__ ci,
                                               const float* __restrict__ w1, u16* __restrict__ W1A) {
    int b = blockIdx.x >> 4, s = blockIdx.x & 15;
    int t = threadIdx.x;
    __shared__ float rce[64], out1[64], ocp[256];
    #pragma unroll 1
    for (int rep = 0; rep < REP_S; rep++) {
        __syncthreads();                            // prior rep's reads done
        float cew = ce[0], gdw = gd[0], gd2w = gd2[0];
        if (t < 64) {
            float r = fmaxf(gl1[b * 64 + t] * cew, 0.f);
            rce[t] = r;
            out1[t] = r * gdw;
        }
        __syncthreads();
        {
            int p = t >> 5, oi = t & 31;
            float sv = 0.f;
            #pragma unroll
            for (int g = 0; g < 8; g++) sv += rce[p * 8 + g] * ci[oi * 8 + g];
            ocp[t] = fmaxf(sv, 0.f) * gd2w;
        }
        __syncthreads();
        u16* Wb = W1A + b * 256 * 64;
        #pragma unroll
        for (int i = 0; i < 4; i++) {
            int idx = s * 1024 + i * 256 + t;
            int o = idx >> 6, c = idx & 63;
            float v = out1[c] + ocp[o];
            Wb[idx] = f2bf(fsig(v) * w1[idx]);
        }
    }
}

// h2p interior = gelu( W1A[b] (256x64) @ x-slab (64 x 48px) ); half-row per block.
// Fused: x load+transpose via LDS slab; 3x3-pool maxes via butterfly + atomicMax(fenc).
__global__ __launch_bounds__(256) void k_gemm1(const u16* __restrict__ W1A, const float* __restrict__ x,
                                               u16* __restrict__ h2p, u32* __restrict__ gl2u) {
    int bi = blockIdx.x;
    int b = bi / 192, rem = bi % 192;
    int y = rem >> 1, half = rem & 1;
    int t = threadIdx.x, wave = t >> 6, lane = t & 63, l15 = lane & 15, quad = lane >> 4;

    __shared__ __align__(16) u16 xs[48 * 72];       // [px][c], row pad 72 (144 B, 16B-mult)
    const float* xb = x + (b * 64) * 9216 + y * 96 + half * 48;
    const float2* xb2 = (const float2*)xb;          // 8B-aligned (all offsets even floats)
    #pragma unroll
    for (int i = 0; i < 6; i++) {
        int idx = i * 256 + t;                      // 1536 = 64c x 24 px-pairs
        int c = idx / 24, px2 = idx - c * 24;
        float2 v = xb2[c * 4608 + px2];
        int px = px2 * 2;
        xs[px * 72 + c] = f2bf(v.x);
        xs[(px + 1) * 72 + c] = f2bf(v.y);
    }
    __syncthreads();

    float4x acc[4][3];
    #pragma unroll
    for (int mt = 0; mt < 4; mt++)
        #pragma unroll
        for (int nt = 0; nt < 3; nt++) acc[mt][nt] = (float4x){0.f, 0.f, 0.f, 0.f};
    const u16* Wb = W1A + b * 256 * 64;
    #pragma unroll
    for (int c0 = 0; c0 < 64; c0 += 32) {
        short8x bfr[3];
        #pragma unroll
        for (int nt = 0; nt < 3; nt++)
            bfr[nt] = *(const short8x*)(xs + (nt * 16 + l15) * 72 + c0 + quad * 8);
        #pragma unroll
        for (int mt = 0; mt < 4; mt++) {
            int oc = wave * 64 + mt * 16 + l15;
            short8x afr = *(const short8x*)(Wb + oc * 64 + c0 + quad * 8);
            #pragma unroll
            for (int nt = 0; nt < 3; nt++)
                acc[mt][nt] = __builtin_amdgcn_mfma_f32_16x16x32_bf16(afr, bfr[nt], acc[mt][nt], 0, 0, 0);
        }
    }
    float gf[4][3][4];
    #pragma unroll
    for (int mt = 0; mt < 4; mt++) {
        #pragma unroll
        for (int nt = 0; nt < 3; nt++) {
            int xx = half * 48 + nt * 16 + l15;
            int oc0 = wave * 64 + mt * 16 + quad * 4;
            int g = oc0 >> 5, cl = oc0 & 31;
            u16 pk[4];
            #pragma unroll
            for (int r = 0; r < 4; r++) {
                float gl = fgelu(acc[mt][nt][r]);   // exact-GELU via A-S erf (1.5e-7)
                gf[mt][nt][r] = gl;
                pk[r] = f2bf(gl);
            }
            u16* dst = h2p + ((((b * 8 + g) * 98 + y + 1) * 98) + xx + 1) * 32 + cl;
            *(ushort4*)dst = make_ushort4(pk[0], pk[1], pk[2], pk[3]);
        }
    }
    // 3x3-pool partial maxes: butterfly over 16 px lanes, then atomicMax(fenc)
    int ki = y >> 5;
    int kA = ki * 3 + (half == 0 ? 0 : 1);
    int kB = ki * 3 + (half == 0 ? 1 : 2);
    #pragma unroll
    for (int mt = 0; mt < 4; mt++) {
        float vA[4], vB[4];
        #pragma unroll
        for (int r = 0; r < 4; r++) {
            if (half == 0) { vA[r] = fmaxf(gf[mt][0][r], gf[mt][1][r]); vB[r] = gf[mt][2][r]; }
            else           { vA[r] = gf[mt][0][r]; vB[r] = fmaxf(gf[mt][1][r], gf[mt][2][r]); }
        }
        #pragma unroll
        for (int m = 1; m < 16; m <<= 1) {
            #pragma unroll
            for (int r = 0; r < 4; r++) {
                vA[r] = fmaxf(vA[r], __shfl_xor(vA[r], m));
                vB[r] = fmaxf(vB[r], __shfl_xor(vB[r], m));
            }
        }
        if (l15 == 0) {
            #pragma unroll
            for (int r = 0; r < 4; r++) {
                int oc = wave * 64 + mt * 16 + quad * 4 + r;
                atomicMax(&gl2u[(b * 9 + kA) * 256 + oc], fenc(vA[r]));
                atomicMax(&gl2u[(b * 9 + kB) * 256 + oc], fenc(vB[r]));
            }
        }
    }
}

// Fused fc2 gating: each of 64 blocks (b,slice) decodes gl2, computes out2/ocp2
// (redundantly per block), writes its W2A slice.
// DIAGNOSTIC: body repeated REP_S times (idempotent).
__global__ __launch_bounds__(256) void k_gate2(const u32* __restrict__ gl2u,
                                               const float* __restrict__ ce, const float* __restrict__ gd,
                                               const float* __restrict__ gd2, const float* __restrict__ ci,
                                               const float* __restrict__ w2, u16* __restrict__ W2A) {
    int b = blockIdx.x >> 4, s = blockIdx.x & 15;
    int t = threadIdx.x;
    __shared__ float rce[256][5];
    __shared__ float out2[256][9];
    __shared__ float ocp2[64][9];
    #pragma unroll 1
    for (int rep = 0; rep < REP_S; rep++) {
        __syncthreads();                            // prior rep's reads done
        {
            float gl[9];
            #pragma unroll
            for (int k = 0; k < 9; k++) gl[k] = fdec(gl2u[(b * 9 + k) * 256 + t]);
            float r[5];
            #pragma unroll
            for (int n = 0; n < 5; n++) {
                float sv = 0.f;
                #pragma unroll
                for (int k = 0; k < 9; k++) sv += gl[k] * ce[n * 9 + k];
                r[n] = fmaxf(sv, 0.f);
                rce[t][n] = r[n];
            }
            #pragma unroll
            for (int k = 0; k < 9; k++) {
                float sv = 0.f;
                #pragma unroll
                for (int n = 0; n < 5; n++) sv += r[n] * gd[k * 5 + n];
                out2[t][k] = sv;
            }
        }
        __syncthreads();
        if (t < 64) {
            int p = t >> 1, oi = t & 1;
            float rt[5];
            #pragma unroll
            for (int n = 0; n < 5; n++) {
                float sv = 0.f;
                #pragma unroll
                for (int g = 0; g < 8; g++) sv += rce[p * 8 + g][n] * ci[oi * 8 + g];
                rt[n] = fmaxf(sv, 0.f);
            }
            #pragma unroll
            for (int k = 0; k < 9; k++) {
                float sv = 0.f;
                #pragma unroll
                for (int n = 0; n < 5; n++) sv += rt[n] * gd2[k * 5 + n];
                ocp2[t][k] = sv;
            }
        }
        __syncthreads();
        u16* Wb = W2A + b * (8 * 9 * 64 * 32);
        for (int it = 0; it < 36; it++) {
            int flat = s * 9216 + it * 256 + t;
            int cl = flat & 31;
            int o = (flat >> 5) & 63;
            int rest = flat >> 11;           // = g*9 + k
            int k = rest % 9, g = rest / 9;
            int c = g * 32 + cl;
            float v = out2[c][k] + ocp2[o][k];
            Wb[flat] = f2bf(fsig(v) * w2[(o * 256 + c) * 9 + k]);
        }
    }
}

// out[b][oc][y][x] = sum_{g,k,cl} W2A[b][g][k][oc][cl] * h2p[b][g][y+i][x+j][cl]
// Block = (b, y, px-half): 768 blocks x 256 thr, __launch_bounds__(256,3).
// Staging: global_load_lds 16B, linear LDS dest, double-buffered, one barrier/g.
// XOR-swizzle (16B-unit involution f(iu)=iu^((iu>>3)&3)) on BOTH pre-swizzled
// global source and read addr -> 2-way conflicts (free).
// acc order (g outer, k inner) unchanged -> bitwise-identical output.
__global__ __launch_bounds__(256, 3) void k_conv2(const u16* __restrict__ W2A, const u16* __restrict__ h2p,
                                                  float* __restrict__ out) {
    int bi = blockIdx.x;
    int b = bi / 192, rem = bi % 192;
    int y = rem >> 1, half = rem & 1;
    int t = threadIdx.x, wave = t >> 6, lane = t & 63, l15 = lane & 15, quad = lane >> 4;
    __shared__ __align__(16) u16 Bls[2][3 * 50 * 32];   // 2 x 9,600 B (4800 u16 each)

    // pre-swizzled per-thread global offsets: linear 16B-unit i = t + j*256,
    // source unit is = f(i) = i ^ ((i>>3)&3); then r = is/200, c16 = is%200.
    int offs[3];
    #pragma unroll
    for (int j = 0; j < 3; j++) {
        int i = t + j * 256;
        int is = i ^ ((i >> 3) & 3);
        int r = is / 200, c16 = is - r * 200;
        offs[j] = ((y + r) * 98 + half * 48) * 32 + c16 * 8;   // u16 units
    }
    const int plane_sz = 98 * 98 * 32;
    int wb = wave * 512;                 // per-wave-uniform LDS u16 offset (lane*16B added by HW)

    {   // prologue: stage g=0 into buf 0
        const u16* pl = h2p + (b * 8) * plane_sz;
        u16* d = &Bls[0][0];
        gl_lds16(pl + offs[0], d + wb);
        gl_lds16(pl + offs[1], d + 2048 + wb);
        if (t < 88) gl_lds16(pl + offs[2], d + 4096 + wb);
    }

    float4x acc[3];
    #pragma unroll
    for (int nt = 0; nt < 3; nt++) acc[nt] = (float4x){0.f, 0.f, 0.f, 0.f};

    for (int g = 0; g < 8; g++) {
        __syncthreads();                 // buf[g&1] staged (vmcnt drained) + prior reads done
        if (g < 7) {                     // issue g+1 DMA into other buffer; overlaps MFMAs
            const u16* pl = h2p + (b * 8 + g + 1) * plane_sz;
            u16* d = &Bls[(g + 1) & 1][0];
            gl_lds16(pl + offs[0], d + wb);
            gl_lds16(pl + offs[1], d + 2048 + wb);
            if (t < 88) gl_lds16(pl + offs[2], d + 4096 + wb);
        }
        const u16* Wg = W2A + (b * 8 + g) * (9 * 64 * 32);
        const u16* Bcur = Bls[g & 1];
        #pragma unroll
        for (int k = 0; k < 9; k++) {
            int ki = k / 3, kj = k - ki * 3;
            // A-frag: oc rows [wave*16, +16), one coalesced 1024B global load per wave
            short8x af = *(const short8x*)(Wg + (k * 64 + wave * 16 + l15) * 32 + quad * 8);
            #pragma unroll
            for (int nt = 0; nt < 3; nt++) {
                int pxl = nt * 16 + l15 + kj;      // local px in [0,50)
                int row = ki * 50 + pxl;
                int qs = quad ^ ((row >> 1) & 3);  // swizzled 16B quarter
                short8x bf = *(const short8x*)(Bcur + row * 32 + qs * 8);
                acc[nt] = __builtin_amdgcn_mfma_f32_16x16x32_bf16(af, bf, acc[nt], 0, 0, 0);
            }
        }
    }
    #pragma unroll
    for (int nt = 0; nt < 3; nt++) {
        int xx = half * 48 + nt * 16 + l15;
        #pragma unroll
        for (int r = 0; r < 4; r++) {
            int oc = wave * 16 + quad * 4 + r;
            out[((b * 64 + oc) * 96 + y) * 96 + xx] = acc[nt][r];
        }
    }
}

extern "C" void kernel_launch(void* const* d_in, const int* in_sizes, int n_in,
                              void* d_out, int out_size, void* d_ws, size_t ws_size,
                              hipStream_t stream) {
    const float* x    = (const float*)d_in[0];
    const float* w1   = (const float*)d_in[1];
    const float* ce1  = (const float*)d_in[2];
    const float* gd1  = (const float*)d_in[3];
    const float* gd21 = (const float*)d_in[4];
    const float* ci1  = (const float*)d_in[5];
    const float* w2   = (const float*)d_in[6];
    const float* ce2  = (const float*)d_in[7];
    const float* gd2  = (const float*)d_in[8];
    const float* gd22 = (const float*)d_in[9];
    const float* ci2  = (const float*)d_in[10];
    float* out = (float*)d_out;

    char* ws = (char*)d_ws;
    u16*   h2p  = (u16*)(ws + 4718592);
    u16*   W1A  = (u16*)(ws + 24387584);
    u16*   W2A  = (u16*)(ws + 24518656);
    float* gl1  = (float*)(ws + 25698304);
    u32*   gl2u = (u32*)(ws + 25796608);

    k_gl1  <<<288, 256, 0, stream>>>(x, gl1, (u32*)h2p, gl2u);
    k_gate1<<<64,  256, 0, stream>>>(gl1, ce1, gd1, gd21, ci1, w1, W1A);
    k_gemm1<<<768, 256, 0, stream>>>(W1A, x, h2p, gl2u);
    k_gate2<<<64,  256, 0, stream>>>(gl2u, ce2, gd2, gd22, ci2, w2, W2A);
    k_conv2<<<768, 256, 0, stream>>>(W2A, h2p, out);
}

// Round 9
// 133.356 us; speedup vs baseline: 1.2565x; 1.2565x over previous
//
#include <hip/hip_runtime.h>
#include <math.h>

typedef __attribute__((ext_vector_type(8))) short short8x;   // 8 x bf16 = 4 VGPRs
typedef __attribute__((ext_vector_type(4))) float float4x;   // MFMA 16x16 C/D frag
typedef unsigned short u16;
typedef unsigned int u32;

// ---- global_load_lds 16B: direct HBM/L2 -> LDS DMA (no VGPR round-trip)
typedef const u32 __attribute__((address_space(1)))* gas_p;
typedef u32 __attribute__((address_space(3)))* las_p;
__device__ __forceinline__ void gl_lds16(const void* g, void* l) {
    __builtin_amdgcn_global_load_lds((gas_p)g, (las_p)l, 16, 0, 0);
}

__device__ __forceinline__ float bf2f(u16 u) {
    return __uint_as_float(((u32)u) << 16);
}
__device__ __forceinline__ u16 f2bf(float f) {
    u32 u = __float_as_uint(f);
    u32 r = (u + 0x7fffu + ((u >> 16) & 1u)) >> 16;   // round-to-nearest-even
    return (u16)r;
}
// monotone float<->u32 mapping (u-order == f-order), exact; for atomicMax on floats
__device__ __forceinline__ u32 fenc(float f) {
    u32 b = __float_as_uint(f);
    return b ^ (0x80000000u | (u32)((int)b >> 31));
}
__device__ __forceinline__ float fdec(u32 u) {
    u32 b = (u & 0x80000000u) ? (u ^ 0x80000000u) : ~u;
    return __uint_as_float(b);
}
// fast sigmoid (v_exp_f32 path); error ~2ulp, rounded to bf16 downstream anyway
__device__ __forceinline__ float fsig(float v) {
    return __builtin_amdgcn_rcpf(1.f + __expf(-v));
}
// fast exact-GELU: Abramowitz-Stegun 7.1.26 erf, max abs err 1.5e-7 (<< bf16 ulp).
__device__ __forceinline__ float fgelu(float v) {
    const float is2 = 0.70710678118654752f;
    float z = v * is2;
    float ax = fabsf(z);
    float t = __builtin_amdgcn_rcpf(1.f + 0.3275911f * ax);
    float p = ((((1.061405429f * t - 1.453152027f) * t) + 1.421413741f) * t - 0.284496736f) * t
              + 0.254829592f;
    float e = 1.f - p * t * __expf(-ax * ax);        // erf(|z|)
    float er = copysignf(e, z);
    return 0.5f * v * (1.f + er);
}

// ---------------------------------------------------------------- sizes
// B=4, H=W=96, C_in=64, C_hid=256, C_out=64, padded HP=98. c split: 8 groups x 32.
// 5-dispatch pipeline: gl1(+border+gl2init) -> gate1 -> gemm1 -> gate2 -> conv2.
// BUDGET LEDGER (all measured):
//   r14: gemm1+conv2 ~= 34.5 us (conv2 ~25: MfmaUtil 18%, stall-bound; MFMA floor 1.5)
//   r16: gl1+gate1+gate2 ~= 5.1 us
//   r12: dispatch boundary <= 2 us each
//   fixed remainder ~= 90 us ~= 2 x 45-us 256-MiB poison fills (harness, in timed
//   replay, NOT kernel-addressable). Achievable frontier ~= 92 + kernels.
// r15 (occupancy 3blk/CU + gl_lds staging + verified conflict-free swizzle): delta
// ~0 -> the remaining conv2 stall is the 8 serial barrier phases, each draining
// staging DMA (syncthreads forces vmcnt(0)) with only 27 MFMAs (~135cy) to hide
// ~600-900cy latency. ROUND-17: stage TWO g-planes per phase -> 4 phases, 54
// MFMAs/phase, half the drains. LDS 38.4KB, still 3 blk/CU. Same acc order.
// NOTE (round-5): border-zero/gl2-init must precede gemm1 via dispatch boundary.
// NOTE (round-10 FAILED): conv2 wave-split regressed (wider barriers). (round-11
// FAILED): never hand-roll cross-block sync (XCD L2 non-coherence). (round-12):
// folding gates is neutral.
// ws layout (bytes):
//   h2p   @ 4718592   : 4*8*98*98*32*2= 19,668,992 bf16 [b][g][98][98][32]
//   W1A   @ 24387584  : 4*256*64*2    = 131,072    bf16 [b][oc][c64]
//   W2A   @ 24518656  : 4*8*9*64*32*2 = 1,179,648  bf16 [b][g][k][oc][c32]
//   gl1   @ 25698304  : 4*64*4       = 1,024      fp32 per-(b,c) global max
//   gl2   @ 25796608  : 4*9*256*4    = 36,864     u32 fenc(max) [b][k=ki*3+kj][c]

// blocks 0..255: global max per (b,c); blocks 256..287: h2p border zero + gl2 init
__global__ __launch_bounds__(256) void k_gl1(const float* __restrict__ x, float* __restrict__ gl1,
                                             u32* __restrict__ h2p32, u32* __restrict__ gl2u) {
    if (blockIdx.x >= 256) {                        // border-zero duty (plane bi)
        int t = threadIdx.x;
        int plane_id = blockIdx.x - 256;
        u32* plane = h2p32 + plane_id * (98 * 98 * 16);
        for (int i = t; i < 1568; i += 256) plane[i] = 0u;                  // row 0
        for (int i = t; i < 1568; i += 256) plane[97 * 98 * 16 + i] = 0u;   // row 97
        for (int i = t; i < 3072; i += 256) {                               // cols 0 & 97
            int r = (i >> 5) + 1;
            int p = ((i >> 4) & 1) * 97;
            int w = i & 15;
            plane[(r * 98 + p) * 16 + w] = 0u;
        }
        // gl2 init to u32 0 (== most-negative in fenc order); 9216 u32 over 32 blocks
        for (int i = plane_id * 288 + t; i < (plane_id + 1) * 288; i += 256)
            gl2u[i] = 0u;
        return;
    }
    int b = blockIdx.x >> 6, c = blockIdx.x & 63;
    const float4* p = (const float4*)(x + (b * 64 + c) * 9216);
    float m = -1e30f;
    #pragma unroll
    for (int i = 0; i < 9; i++) {
        float4 v = p[i * 256 + threadIdx.x];
        m = fmaxf(m, fmaxf(fmaxf(v.x, v.y), fmaxf(v.z, v.w)));
    }
    __shared__ float red[256];
    red[threadIdx.x] = m;
    __syncthreads();
    for (int s = 128; s > 0; s >>= 1) {
        if (threadIdx.x < s) red[threadIdx.x] = fmaxf(red[threadIdx.x], red[threadIdx.x + s]);
        __syncthreads();
    }
    if (threadIdx.x == 0) gl1[b * 64 + c] = red[0];
}

// fc1 gating -> W1A[b][oc=256][c=64]; 64 blocks = (b, slice16)
__global__ __launch_bounds__(256) void k_gate1(const float* __restrict__ gl1,
                                               const float* __restrict__ ce, const float* __restrict__ gd,
                                               const float* __restrict__ gd2, const float* __restrict__ ci,
                                               const float* __restrict__ w1, u16* __restrict__ W1A) {
    int b = blockIdx.x >> 4, s = blockIdx.x & 15;
    int t = threadIdx.x;
    __shared__ float rce[64], out1[64], ocp[256];
    float cew = ce[0], gdw = gd[0], gd2w = gd2[0];
    if (t < 64) {
        float r = fmaxf(gl1[b * 64 + t] * cew, 0.f);
        rce[t] = r;
        out1[t] = r * gdw;
    }
    __syncthreads();
    {
        int p = t >> 5, oi = t & 31;
        float sv = 0.f;
        #pragma unroll
        for (int g = 0; g < 8; g++) sv += rce[p * 8 + g] * ci[oi * 8 + g];
        ocp[t] = fmaxf(sv, 0.f) * gd2w;
    }
    __syncthreads();
    u16* Wb = W1A + b * 256 * 64;
    #pragma unroll
    for (int i = 0; i < 4; i++) {
        int idx = s * 1024 + i * 256 + t;
        int o = idx >> 6, c = idx & 63;
        float v = out1[c] + ocp[o];
        Wb[idx] = f2bf(fsig(v) * w1[idx]);
    }
}

// h2p interior = gelu( W1A[b] (256x64) @ x-slab (64 x 48px) ); half-row per block.
// Fused: x load+transpose via LDS slab; 3x3-pool maxes via butterfly + atomicMax(fenc).
__global__ __launch_bounds__(256) void k_gemm1(const u16* __restrict__ W1A, const float* __restrict__ x,
                                               u16* __restrict__ h2p, u32* __restrict__ gl2u) {
    int bi = blockIdx.x;
    int b = bi / 192, rem = bi % 192;
    int y = rem >> 1, half = rem & 1;
    int t = threadIdx.x, wave = t >> 6, lane = t & 63, l15 = lane & 15, quad = lane >> 4;

    __shared__ __align__(16) u16 xs[48 * 72];       // [px][c], row pad 72 (144 B, 16B-mult)
    const float* xb = x + (b * 64) * 9216 + y * 96 + half * 48;
    const float2* xb2 = (const float2*)xb;          // 8B-aligned (all offsets even floats)
    #pragma unroll
    for (int i = 0; i < 6; i++) {
        int idx = i * 256 + t;                      // 1536 = 64c x 24 px-pairs
        int c = idx / 24, px2 = idx - c * 24;
        float2 v = xb2[c * 4608 + px2];
        int px = px2 * 2;
        xs[px * 72 + c] = f2bf(v.x);
        xs[(px + 1) * 72 + c] = f2bf(v.y);
    }
    __syncthreads();

    float4x acc[4][3];
    #pragma unroll
    for (int mt = 0; mt < 4; mt++)
        #pragma unroll
        for (int nt = 0; nt < 3; nt++) acc[mt][nt] = (float4x){0.f, 0.f, 0.f, 0.f};
    const u16* Wb = W1A + b * 256 * 64;
    #pragma unroll
    for (int c0 = 0; c0 < 64; c0 += 32) {
        short8x bfr[3];
        #pragma unroll
        for (int nt = 0; nt < 3; nt++)
            bfr[nt] = *(const short8x*)(xs + (nt * 16 + l15) * 72 + c0 + quad * 8);
        #pragma unroll
        for (int mt = 0; mt < 4; mt++) {
            int oc = wave * 64 + mt * 16 + l15;
            short8x afr = *(const short8x*)(Wb + oc * 64 + c0 + quad * 8);
            #pragma unroll
            for (int nt = 0; nt < 3; nt++)
                acc[mt][nt] = __builtin_amdgcn_mfma_f32_16x16x32_bf16(afr, bfr[nt], acc[mt][nt], 0, 0, 0);
        }
    }
    float gf[4][3][4];
    #pragma unroll
    for (int mt = 0; mt < 4; mt++) {
        #pragma unroll
        for (int nt = 0; nt < 3; nt++) {
            int xx = half * 48 + nt * 16 + l15;
            int oc0 = wave * 64 + mt * 16 + quad * 4;
            int g = oc0 >> 5, cl = oc0 & 31;
            u16 pk[4];
            #pragma unroll
            for (int r = 0; r < 4; r++) {
                float gl = fgelu(acc[mt][nt][r]);   // exact-GELU via A-S erf (1.5e-7)
                gf[mt][nt][r] = gl;
                pk[r] = f2bf(gl);
            }
            u16* dst = h2p + ((((b * 8 + g) * 98 + y + 1) * 98) + xx + 1) * 32 + cl;
            *(ushort4*)dst = make_ushort4(pk[0], pk[1], pk[2], pk[3]);
        }
    }
    // 3x3-pool partial maxes: butterfly over 16 px lanes, then atomicMax(fenc)
    int ki = y >> 5;
    int kA = ki * 3 + (half == 0 ? 0 : 1);
    int kB = ki * 3 + (half == 0 ? 1 : 2);
    #pragma unroll
    for (int mt = 0; mt < 4; mt++) {
        float vA[4], vB[4];
        #pragma unroll
        for (int r = 0; r < 4; r++) {
            if (half == 0) { vA[r] = fmaxf(gf[mt][0][r], gf[mt][1][r]); vB[r] = gf[mt][2][r]; }
            else           { vA[r] = gf[mt][0][r]; vB[r] = fmaxf(gf[mt][1][r], gf[mt][2][r]); }
        }
        #pragma unroll
        for (int m = 1; m < 16; m <<= 1) {
            #pragma unroll
            for (int r = 0; r < 4; r++) {
                vA[r] = fmaxf(vA[r], __shfl_xor(vA[r], m));
                vB[r] = fmaxf(vB[r], __shfl_xor(vB[r], m));
            }
        }
        if (l15 == 0) {
            #pragma unroll
            for (int r = 0; r < 4; r++) {
                int oc = wave * 64 + mt * 16 + quad * 4 + r;
                atomicMax(&gl2u[(b * 9 + kA) * 256 + oc], fenc(vA[r]));
                atomicMax(&gl2u[(b * 9 + kB) * 256 + oc], fenc(vB[r]));
            }
        }
    }
}

// Fused fc2 gating: each of 64 blocks (b,slice) decodes gl2, computes out2/ocp2
// (redundantly per block), writes its W2A slice.
__global__ __launch_bounds__(256) void k_gate2(const u32* __restrict__ gl2u,
                                               const float* __restrict__ ce, const float* __restrict__ gd,
                                               const float* __restrict__ gd2, const float* __restrict__ ci,
                                               const float* __restrict__ w2, u16* __restrict__ W2A) {
    int b = blockIdx.x >> 4, s = blockIdx.x & 15;
    int t = threadIdx.x;
    __shared__ float rce[256][5];
    __shared__ float out2[256][9];
    __shared__ float ocp2[64][9];
    {
        float gl[9];
        #pragma unroll
        for (int k = 0; k < 9; k++) gl[k] = fdec(gl2u[(b * 9 + k) * 256 + t]);
        float r[5];
        #pragma unroll
        for (int n = 0; n < 5; n++) {
            float sv = 0.f;
            #pragma unroll
            for (int k = 0; k < 9; k++) sv += gl[k] * ce[n * 9 + k];
            r[n] = fmaxf(sv, 0.f);
            rce[t][n] = r[n];
        }
        #pragma unroll
        for (int k = 0; k < 9; k++) {
            float sv = 0.f;
            #pragma unroll
            for (int n = 0; n < 5; n++) sv += r[n] * gd[k * 5 + n];
            out2[t][k] = sv;
        }
    }
    __syncthreads();
    if (t < 64) {
        int p = t >> 1, oi = t & 1;
        float rt[5];
        #pragma unroll
        for (int n = 0; n < 5; n++) {
            float sv = 0.f;
            #pragma unroll
            for (int g = 0; g < 8; g++) sv += rce[p * 8 + g][n] * ci[oi * 8 + g];
            rt[n] = fmaxf(sv, 0.f);
        }
        #pragma unroll
        for (int k = 0; k < 9; k++) {
            float sv = 0.f;
            #pragma unroll
            for (int n = 0; n < 5; n++) sv += rt[n] * gd2[k * 5 + n];
            ocp2[t][k] = sv;
        }
    }
    __syncthreads();
    u16* Wb = W2A + b * (8 * 9 * 64 * 32);
    for (int it = 0; it < 36; it++) {
        int flat = s * 9216 + it * 256 + t;
        int cl = flat & 31;
        int o = (flat >> 5) & 63;
        int rest = flat >> 11;           // = g*9 + k
        int k = rest % 9, g = rest / 9;
        int c = g * 32 + cl;
        float v = out2[c][k] + ocp2[o][k];
        Wb[flat] = f2bf(fsig(v) * w2[(o * 256 + c) * 9 + k]);
    }
}

// out[b][oc][y][x] = sum_{g,k,cl} W2A[b][g][k][oc][cl] * h2p[b][g][y+i][x+j][cl]
// Block = (b, y, px-half): 768 blocks x 256 thr, __launch_bounds__(256,3) -> 3 blk/CU.
// ROUND-17: TWO g-planes staged per phase -> 4 barrier phases (was 8), 54 MFMAs
// per phase to hide staging latency, half the vmcnt(0) barrier drains.
// LDS 2 bufs x 2 slots x 9.6KB = 38.4KB (115.2KB/CU at 3 blocks: fits 160KB).
// Staging: global_load_lds 16B, linear LDS dest. XOR-swizzle (16B-unit involution
// f(iu)=iu^((iu>>3)&3)) on BOTH pre-swizzled global source and read addr ->
// conflict-free (verified: each 8-lane group covers all 8 bank windows).
// acc order (g ascending, k ascending) unchanged -> bitwise-identical output.
__global__ __launch_bounds__(256, 3) void k_conv2(const u16* __restrict__ W2A, const u16* __restrict__ h2p,
                                                  float* __restrict__ out) {
    int bi = blockIdx.x;
    int b = bi / 192, rem = bi % 192;
    int y = rem >> 1, half = rem & 1;
    int t = threadIdx.x, wave = t >> 6, lane = t & 63, l15 = lane & 15, quad = lane >> 4;
    __shared__ __align__(16) u16 Bls[2][2][3 * 50 * 32];   // [buf][gslot] 2x2x9600 B

    // pre-swizzled per-thread global offsets: linear 16B-unit i = t + j*256,
    // source unit is = f(i) = i ^ ((i>>3)&3); then r = is/200, c16 = is%200.
    int offs[3];
    #pragma unroll
    for (int j = 0; j < 3; j++) {
        int i = t + j * 256;
        int is = i ^ ((i >> 3) & 3);
        int r = is / 200, c16 = is - r * 200;
        offs[j] = ((y + r) * 98 + half * 48) * 32 + c16 * 8;   // u16 units
    }
    const int plane_sz = 98 * 98 * 32;
    int wb = wave * 512;                 // per-wave-uniform LDS u16 offset (lane*16B added by HW)

    {   // prologue: stage pair 0 (g=0,1) into buf 0
        const u16* pl = h2p + (b * 8) * plane_sz;
        #pragma unroll
        for (int gg = 0; gg < 2; gg++) {
            u16* d = &Bls[0][gg][0];
            gl_lds16(pl + gg * plane_sz + offs[0], d + wb);
            gl_lds16(pl + gg * plane_sz + offs[1], d + 2048 + wb);
            if (t < 88) gl_lds16(pl + gg * plane_sz + offs[2], d + 4096 + wb);
        }
    }

    float4x acc[3];
    #pragma unroll
    for (int nt = 0; nt < 3; nt++) acc[nt] = (float4x){0.f, 0.f, 0.f, 0.f};

    for (int s = 0; s < 4; s++) {
        __syncthreads();                 // buf[s&1] staged (vmcnt drained) + prior reads done
        if (s < 3) {                     // issue next-pair DMA into other buffer; overlaps MFMAs
            const u16* pl = h2p + (b * 8 + 2 * (s + 1)) * plane_sz;
            #pragma unroll
            for (int gg = 0; gg < 2; gg++) {
                u16* d = &Bls[(s + 1) & 1][gg][0];
                gl_lds16(pl + gg * plane_sz + offs[0], d + wb);
                gl_lds16(pl + gg * plane_sz + offs[1], d + 2048 + wb);
                if (t < 88) gl_lds16(pl + gg * plane_sz + offs[2], d + 4096 + wb);
            }
        }
        #pragma unroll
        for (int gg = 0; gg < 2; gg++) {
            int g = 2 * s + gg;
            const u16* Wg = W2A + (b * 8 + g) * (9 * 64 * 32);
            const u16* Bcur = &Bls[s & 1][gg][0];
            #pragma unroll
            for (int k = 0; k < 9; k++) {
                int ki = k / 3, kj = k - ki * 3;
                // A-frag: oc rows [wave*16, +16), one coalesced 1024B global load per wave
                short8x af = *(const short8x*)(Wg + (k * 64 + wave * 16 + l15) * 32 + quad * 8);
                #pragma unroll
                for (int nt = 0; nt < 3; nt++) {
                    int pxl = nt * 16 + l15 + kj;      // local px in [0,50)
                    int row = ki * 50 + pxl;
                    int qs = quad ^ ((row >> 1) & 3);  // swizzled 16B quarter
                    short8x bf = *(const short8x*)(Bcur + row * 32 + qs * 8);
                    acc[nt] = __builtin_amdgcn_mfma_f32_16x16x32_bf16(af, bf, acc[nt], 0, 0, 0);
                }
            }
        }
    }
    #pragma unroll
    for (int nt = 0; nt < 3; nt++) {
        int xx = half * 48 + nt * 16 + l15;
        #pragma unroll
        for (int r = 0; r < 4; r++) {
            int oc = wave * 16 + quad * 4 + r;
            out[((b * 64 + oc) * 96 + y) * 96 + xx] = acc[nt][r];
        }
    }
}

extern "C" void kernel_launch(void* const* d_in, const int* in_sizes, int n_in,
                              void* d_out, int out_size, void* d_ws, size_t ws_size,
                              hipStream_t stream) {
    const float* x    = (const float*)d_in[0];
    const float* w1   = (const float*)d_in[1];
    const float* ce1  = (const float*)d_in[2];
    const float* gd1  = (const float*)d_in[3];
    const float* gd21 = (const float*)d_in[4];
    const float* ci1  = (const float*)d_in[5];
    const float* w2   = (const float*)d_in[6];
    const float* ce2  = (const float*)d_in[7];
    const float* gd2  = (const float*)d_in[8];
    const float* gd22 = (const float*)d_in[9];
    const float* ci2  = (const float*)d_in[10];
    float* out = (float*)d_out;

    char* ws = (char*)d_ws;
    u16*   h2p  = (u16*)(ws + 4718592);
    u16*   W1A  = (u16*)(ws + 24387584);
    u16*   W2A  = (u16*)(ws + 24518656);
    float* gl1  = (float*)(ws + 25698304);
    u32*   gl2u = (u32*)(ws + 25796608);

    k_gl1  <<<288, 256, 0, stream>>>(x, gl1, (u32*)h2p, gl2u);
    k_gate1<<<64,  256, 0, stream>>>(gl1, ce1, gd1, gd21, ci1, w1, W1A);
    k_gemm1<<<768, 256, 0, stream>>>(W1A, x, h2p, gl2u);
    k_gate2<<<64,  256, 0, stream>>>(gl2u, ce2, gd2, gd22, ci2, w2, W2A);
    k_conv2<<<768, 256, 0, stream>>>(W2A, h2p, out);
}